// Round 7
// baseline (345.290 us; speedup 1.0000x reference)
//
#include <hip/hip_runtime.h>

// LowRankRotatedSpaceIntervention — v7: exact-counted vmcnt ring.
// out[b,:] = base[b,:] + (mask_b . ((source[b,:]-base[b,:]) @ W)) @ W^T
// B=16384, D=4096, R=64, 8 partitions of 8, 4 selected per row.
//
// v6 raced because the W-fragment loads were ordinary compiler-scheduled
// loads — hoisting them across my s_waitcnt silently broke the count.
// v7: in the phase-1 loop EVERY VMEM op is order-pinned:
//   - base/src staging: global_load_lds builtins (memory-writing intrinsics,
//     order preserved, cannot cross memory-clobbered asm)
//   - W fragments: 8 global_load_dwordx4 inside ONE asm volatile block
// Ledger (groups in issue order): s(c)[4] W(c)[8] s(c+1)[4] W(c+1)[8] s(c+2)[4]
//   -> s_waitcnt vmcnt(16) provably drains s(c)+W(c), keeps 16 ops in flight.
// Ring-3 LDS staging, W double-buffered in registers (parity-static indexing).
// 1-wave blocks (64 thr, 8 rows), 2048 blocks -> 8 waves/CU, no barriers.

#define D_DIM 4096
#define R_DIM 64
#define ROWS  8
#define NCH   64

typedef short bf16vec8 __attribute__((ext_vector_type(8)));
typedef float f32x4v  __attribute__((ext_vector_type(4)));
typedef unsigned int u32x4 __attribute__((ext_vector_type(4)));

#define OFF_RM      12288      // after 3 x 4KB ring; [8][72] bf16 = 1152 B
#define SMEM_BYTES  13440

// exact-count wait: memory clobber fences all memory ops; sched_barrier
// stops register-only MFMA from hoisting above (rule #18).
#define VMWAIT(N)                                              \
  do {                                                         \
    asm volatile("s_waitcnt vmcnt(" #N ")" ::: "memory");      \
    __builtin_amdgcn_sched_barrier(0);                         \
  } while (0)

__device__ __forceinline__ unsigned int f2bf_u(float f) {
  unsigned int u = __builtin_bit_cast(unsigned int, f);
  return (u + 0x7fffu + ((u >> 16) & 1u)) >> 16;   // RNE
}
__device__ __forceinline__ unsigned int pack2bf(float a, float b) {
  return f2bf_u(a) | (f2bf_u(b) << 16);
}
__device__ __forceinline__ void async_ld16(const void* gp, void* lp) {
  __builtin_amdgcn_global_load_lds(
      (const __attribute__((address_space(1))) void*)gp,
      (__attribute__((address_space(3))) void*)lp, 16, 0, 0);
}

__global__ __launch_bounds__(256)
void lrri_prep(const float* __restrict__ W, unsigned short* __restrict__ Wt,
               unsigned short* __restrict__ Wb) {
  const int idx = blockIdx.x * blockDim.x + threadIdx.x;   // 0..65535
  const int k = idx >> 4;
  const int j = (idx & 15) * 4;
  float4 w = *(const float4*)(W + (size_t)k * R_DIM + j);
  ushort4 p;
  p.x = (unsigned short)f2bf_u(w.x);
  p.y = (unsigned short)f2bf_u(w.y);
  p.z = (unsigned short)f2bf_u(w.z);
  p.w = (unsigned short)f2bf_u(w.w);
  *(ushort4*)(Wb + (size_t)k * R_DIM + j) = p;     // [4096][64] bf16
  Wt[(size_t)(j + 0) * D_DIM + k] = p.x;           // [64][4096] bf16
  Wt[(size_t)(j + 1) * D_DIM + k] = p.y;
  Wt[(size_t)(j + 2) * D_DIM + k] = p.z;
  Wt[(size_t)(j + 3) * D_DIM + k] = p.w;
}

template<bool USE_WS>
__global__ __launch_bounds__(64)
void lrri_fused(const float* __restrict__ base, const float* __restrict__ srcp,
                const float* __restrict__ W, const int* __restrict__ subs,
                const unsigned short* __restrict__ Wt_bf,   // [64][4096]
                const unsigned short* __restrict__ Wb_bf,   // [4096][64]
                float* __restrict__ out)
{
  __shared__ __align__(16) unsigned char smem[SMEM_BYTES];
  const int tid  = threadIdx.x;
  const int l4   = tid & 15;
  const int g    = tid >> 4;
  const long rowbase = (long)blockIdx.x * ROWS;

  // stage chunk c into ring buffer (c%3): 8 rows x 256B of base and src.
  // LDS layout per buffer: [0,2048) base row-major [8][256B], [2048,4096) src.
  auto stage = [&](int c) {
    unsigned char* buf = smem + (c % 3) * 4096;
    const int kb = c * 64;
    #pragma unroll
    for (int i = 0; i < 2; ++i) {
      const long goff = (rowbase + i * 4 + g) * (long)D_DIM + kb + l4 * 4;
      async_ld16(base + goff, buf + i * 1024);
    }
    #pragma unroll
    for (int i = 0; i < 2; ++i) {
      const long goff = (rowbase + i * 4 + g) * (long)D_DIM + kb + l4 * 4;
      async_ld16(srcp + goff, buf + 2048 + i * 1024);
    }
  };

  // 8 W-fragment loads (j-tile t=0..3, k-split s=0..1) in ONE asm block:
  // exact vmcnt contribution (8), order pinned relative to builtins.
  auto wload = [&](u32x4 (&dst)[8], int kb) {
    const char* wbp = (const char*)Wt_bf + (size_t)kb * 2 + l4 * 8192 + g * 16;
    const char* a0 = wbp;
    const char* a1 = wbp + 16 * 8192;
    const char* a2 = wbp + 32 * 8192;
    const char* a3 = wbp + 48 * 8192;
    asm volatile(
        "global_load_dwordx4 %0, %8, off\n\t"
        "global_load_dwordx4 %1, %8, off offset:64\n\t"
        "global_load_dwordx4 %2, %9, off\n\t"
        "global_load_dwordx4 %3, %9, off offset:64\n\t"
        "global_load_dwordx4 %4, %10, off\n\t"
        "global_load_dwordx4 %5, %10, off offset:64\n\t"
        "global_load_dwordx4 %6, %11, off\n\t"
        "global_load_dwordx4 %7, %11, off offset:64"
        : "=&v"(dst[0]), "=&v"(dst[1]), "=&v"(dst[2]), "=&v"(dst[3]),
          "=&v"(dst[4]), "=&v"(dst[5]), "=&v"(dst[6]), "=&v"(dst[7])
        : "v"(a0), "v"(a1), "v"(a2), "v"(a3)
        : "memory");
  };

  f32x4v acc[4];
  #pragma unroll
  for (int t = 0; t < 4; ++t) acc[t] = (f32x4v){0.f, 0.f, 0.f, 0.f};

  // consume chunk c: ds_read A rows, diff->bf16 pack, 8 MFMA with wf regs
  auto ph1_compute = [&](int c, const u32x4 (&wf)[8]) {
    const unsigned char* buf = smem + (c % 3) * 4096;
    u32x4 af[2] = {{0u,0u,0u,0u},{0u,0u,0u,0u}};
    if (l4 < ROWS) {
      #pragma unroll
      for (int s = 0; s < 2; ++s) {
        const int bo = l4 * 256 + s * 128 + g * 32;
        float4 fb0 = *(const float4*)(buf + bo);
        float4 fb1 = *(const float4*)(buf + bo + 16);
        float4 fs0 = *(const float4*)(buf + 2048 + bo);
        float4 fs1 = *(const float4*)(buf + 2048 + bo + 16);
        af[s].x = pack2bf(fs0.x - fb0.x, fs0.y - fb0.y);
        af[s].y = pack2bf(fs0.z - fb0.z, fs0.w - fb0.w);
        af[s].z = pack2bf(fs1.x - fb1.x, fs1.y - fb1.y);
        af[s].w = pack2bf(fs1.z - fb1.z, fs1.w - fb1.w);
      }
    }
    #pragma unroll
    for (int t = 0; t < 4; ++t)
      #pragma unroll
      for (int s = 0; s < 2; ++s)
        acc[t] = __builtin_amdgcn_mfma_f32_16x16x32_bf16(
            __builtin_bit_cast(bf16vec8, af[s]),
            __builtin_bit_cast(bf16vec8, wf[t * 2 + s]), acc[t], 0, 0, 0);
  };

  // ---------------- Phase 1 -----------------------------------------------
  if constexpr (USE_WS) {
    u32x4 wb0[8], wb1[8];
    stage(0); wload(wb0, 0); stage(1); wload(wb1, 64);   // queue: s0 W0 s1 W1
    #pragma unroll 1
    for (int cc = 0; cc < 62; cc += 2) {
      stage(cc + 2);               // queue: s(c) W(c) s(c+1) W(c+1) s(c+2)
      VMWAIT(16);                  // drains s(c), W(c); keeps 16 in flight
      ph1_compute(cc, wb0);
      wload(wb0, (cc + 2) * 64);   // W for window cc+2 (even -> wb0)
      stage(cc + 3);
      VMWAIT(16);
      ph1_compute(cc + 1, wb1);
      wload(wb1, (cc + 3) * 64);
    }
    VMWAIT(12);                    // drains s(62), W(62); keeps s63 W63
    ph1_compute(62, wb0);
    VMWAIT(0);
    ph1_compute(63, wb1);
  } else {
    // fallback (no workspace): serial ring-1, full drain each chunk
    #pragma unroll 1
    for (int c = 0; c < NCH; ++c) {
      stage(c);
      VMWAIT(0);
      u32x4 wf[8];
      const int kb = c * 64;
      #pragma unroll
      for (int ts = 0; ts < 8; ++ts) {
        const int t = ts >> 1, s = ts & 1;
        unsigned int pq[4];
        #pragma unroll
        for (int e2 = 0; e2 < 4; ++e2) {
          float wa = W[(size_t)(kb + s * 32 + g * 8 + e2 * 2    ) * R_DIM + t * 16 + l4];
          float wb = W[(size_t)(kb + s * 32 + g * 8 + e2 * 2 + 1) * R_DIM + t * 16 + l4];
          pq[e2] = pack2bf(wa, wb);
        }
        wf[ts].x = pq[0]; wf[ts].y = pq[1]; wf[ts].z = pq[2]; wf[ts].w = pq[3];
      }
      ph1_compute(c, wf);
    }
  }

  // ---------------- Mask + pack rm (wave-private, no barrier) -------------
  // acc layout: row = g*4+i (valid g<2 -> rows 0..7), col = t*16+l4
  if (g < 2) {
    #pragma unroll
    for (int i = 0; i < 4; ++i) {
      const int row = g * 4 + i;
      const int4 sb = *(const int4*)(subs + (size_t)(rowbase + row) * 4);
      const unsigned mbits = (1u << sb.x) | (1u << sb.y) |
                             (1u << sb.z) | (1u << sb.w);
      #pragma unroll
      for (int t = 0; t < 4; ++t) {
        const int j = t * 16 + l4;
        const unsigned short v = ((mbits >> (j >> 3)) & 1u)
                                     ? (unsigned short)f2bf_u(acc[t][i])
                                     : (unsigned short)0;
        ((unsigned short*)(smem + OFF_RM))[row * 72 + j] = v;
      }
    }
  }
  // single wave: ds_write -> ds_read ordering handled by compiler lgkmcnt

  uint4 a2[2] = {{0u,0u,0u,0u},{0u,0u,0u,0u}};
  if (l4 < ROWS) {
    a2[0] = *(const uint4*)(smem + OFF_RM + l4 * 144 + g * 16);
    a2[1] = *(const uint4*)(smem + OFF_RM + l4 * 144 + 64 + g * 16);
  }

  // ---------------- Phase 2: out = base + rm @ W^T ------------------------
  #pragma unroll 2
  for (int grp = 0; grp < 64; ++grp) {
    const int cbase = grp * 64;
    uint4 wb[8];
    if (USE_WS) {
      #pragma unroll
      for (int ts = 0; ts < 8; ++ts) {
        const int t = ts >> 1, s = ts & 1;
        wb[ts] = *(const uint4*)(Wb_bf + (size_t)(cbase + t * 16 + l4) * R_DIM +
                                 s * 32 + g * 8);
      }
    } else {
      #pragma unroll
      for (int ts = 0; ts < 8; ++ts) {
        const int t = ts >> 1, s = ts & 1;
        const float* wp = W + (size_t)(cbase + t * 16 + l4) * R_DIM + s * 32 + g * 8;
        float4 wa = *(const float4*)(wp);
        float4 wc = *(const float4*)(wp + 4);
        wb[ts].x = pack2bf(wa.x, wa.y); wb[ts].y = pack2bf(wa.z, wa.w);
        wb[ts].z = pack2bf(wc.x, wc.y); wb[ts].w = pack2bf(wc.z, wc.w);
      }
    }
    float4 bb[2];
    #pragma unroll
    for (int i2 = 0; i2 < 2; ++i2) {
      const int r = i2 * 4 + g;
      bb[i2] = *(const float4*)(base + (rowbase + r) * (long)D_DIM + cbase + l4 * 4);
    }
    f32x4v a[4];
    #pragma unroll
    for (int t = 0; t < 4; ++t) a[t] = (f32x4v){0.f, 0.f, 0.f, 0.f};
    #pragma unroll
    for (int t = 0; t < 4; ++t) {
      #pragma unroll
      for (int s = 0; s < 2; ++s) {
        a[t] = __builtin_amdgcn_mfma_f32_16x16x32_bf16(
            __builtin_bit_cast(bf16vec8, a2[s]),
            __builtin_bit_cast(bf16vec8, wb[t * 2 + s]), a[t], 0, 0, 0);
      }
    }
    // transpose via dead ring buffers (double-buffered across grp parity)
    float* cbuf = (float*)(smem + (grp & 1) * 4096);
    if (g < 2) {
      #pragma unroll
      for (int t = 0; t < 4; ++t)
        #pragma unroll
        for (int i = 0; i < 4; ++i)
          cbuf[(g * 4 + i) * 72 + t * 16 + l4] = a[t][i];
    }
    #pragma unroll
    for (int i2 = 0; i2 < 2; ++i2) {
      const int r = i2 * 4 + g;
      f32x4v cv = *(const f32x4v*)(cbuf + r * 72 + l4 * 4);
      float4 o;
      o.x = cv[0] + bb[i2].x;
      o.y = cv[1] + bb[i2].y;
      o.z = cv[2] + bb[i2].z;
      o.w = cv[3] + bb[i2].w;
      *(float4*)(out + (rowbase + r) * (long)D_DIM + cbase + l4 * 4) = o;
    }
  }
}

extern "C" void kernel_launch(void* const* d_in, const int* in_sizes, int n_in,
                              void* d_out, int out_size, void* d_ws, size_t ws_size,
                              hipStream_t stream) {
  const float* base = (const float*)d_in[0];
  const float* srcp = (const float*)d_in[1];
  const float* W    = (const float*)d_in[2];
  const int*   subs = (const int*)d_in[3];
  float* out = (float*)d_out;

  const int nblocks = 16384 / ROWS;   // 2048 one-wave blocks
  const size_t wbytes = (size_t)2 * R_DIM * D_DIM * sizeof(unsigned short); // 1 MB
  if (d_ws && ws_size >= wbytes) {
    unsigned short* Wt = (unsigned short*)d_ws;          // [64][4096] bf16
    unsigned short* Wb = Wt + (size_t)R_DIM * D_DIM;     // [4096][64] bf16
    lrri_prep<<<256, 256, 0, stream>>>(W, Wt, Wb);
    lrri_fused<true><<<nblocks, 64, 0, stream>>>(base, srcp, W, subs, Wt, Wb, out);
  } else {
    lrri_fused<false><<<nblocks, 64, 0, stream>>>(base, srcp, W, subs, nullptr, nullptr, out);
  }
}

// Round 8
// 230.968 us; speedup vs baseline: 1.4950x; 1.4950x over previous
//
#include <hip/hip_runtime.h>

// LowRankRotatedSpaceIntervention — v8 = v5 + per-block column-phase stagger.
// out[b,:] = base[b,:] + (mask_b . ((source[b,:]-base[b,:]) @ W)) @ W^T
// B=16384, D=4096, R=64, 8 partitions of 8, 4 selected per row.
//
// R1-R7 elimination: BW pins at 1.8-2.6 TB/s across occupancies 4-16
// waves/CU, LDS/register/async staging, and a provably-16-deep counted
// pipeline => not an MLP limit. Remaining invariant: all blocks sweep
// columns in lockstep on 16-consecutive rows (row stride 16KB aliases to
// ~2 HBM channel values), concentrating the whole GPU on a sliver of the
// channel set at every instant (8 TB/s x ~1/4 coverage ~= observed 2 TB/s).
// v8: rotate each block's chunk order by hash(blockIdx) — phase 1
// ch=(c+7b)&31 (K-sum is commutative), phase 2 ga=(grp+5b)&15 — so at any
// instant different blocks touch different 256B column windows => full
// channel coverage. No other change vs v5.

#define D_DIM 4096
#define R_DIM 64
#define BM    32
#define WAVESTG 16384            // per-wave staging: 2 buffers x 8KB
#define OFF_RM  65536            // [32][72] bf16 = 4608 B
#define SMEM_BYTES 70144

typedef short bf16vec8 __attribute__((ext_vector_type(8)));
typedef float f32x4v  __attribute__((ext_vector_type(4)));

__device__ __forceinline__ unsigned int f2bf_u(float f) {
  unsigned int u = __builtin_bit_cast(unsigned int, f);
  return (u + 0x7fffu + ((u >> 16) & 1u)) >> 16;   // RNE
}
__device__ __forceinline__ unsigned int pack2bf(float a, float b) {
  return f2bf_u(a) | (f2bf_u(b) << 16);
}
__device__ __forceinline__ void async_ld16(const void* g, void* l) {
  __builtin_amdgcn_global_load_lds(
      (const __attribute__((address_space(1))) void*)g,
      (__attribute__((address_space(3))) void*)l, 16, 0, 0);
}

__global__ __launch_bounds__(256)
void lrri_prep(const float* __restrict__ W, unsigned short* __restrict__ Wt,
               unsigned short* __restrict__ Wb) {
  const int idx = blockIdx.x * blockDim.x + threadIdx.x;   // 0..65535
  const int k = idx >> 4;
  const int j = (idx & 15) * 4;
  float4 w = *(const float4*)(W + (size_t)k * R_DIM + j);
  ushort4 p;
  p.x = (unsigned short)f2bf_u(w.x);
  p.y = (unsigned short)f2bf_u(w.y);
  p.z = (unsigned short)f2bf_u(w.z);
  p.w = (unsigned short)f2bf_u(w.w);
  *(ushort4*)(Wb + (size_t)k * R_DIM + j) = p;     // [4096][64] bf16
  Wt[(size_t)(j + 0) * D_DIM + k] = p.x;           // [64][4096] bf16
  Wt[(size_t)(j + 1) * D_DIM + k] = p.y;
  Wt[(size_t)(j + 2) * D_DIM + k] = p.z;
  Wt[(size_t)(j + 3) * D_DIM + k] = p.w;
}

template<bool USE_WS>
__global__ __launch_bounds__(256, 2)
void lrri_fused(const float* __restrict__ base, const float* __restrict__ srcp,
                const float* __restrict__ W, const int* __restrict__ subs,
                const unsigned short* __restrict__ Wt_bf,   // [64][4096]
                const unsigned short* __restrict__ Wb_bf,   // [4096][64]
                float* __restrict__ out)
{
  __shared__ __align__(16) unsigned char smem[SMEM_BYTES];
  const int tid  = threadIdx.x;
  const int wave = tid >> 6;
  const int lane = tid & 63;
  const int l4   = lane & 15;
  const int g    = lane >> 4;
  const int rh   = wave >> 1;            // row-half: 16 rows
  const int kh   = wave & 1;             // K-half: 2048 cols
  const long rowbase = (long)blockIdx.x * BM;
  const long rowg    = rowbase + rh * 16;
  unsigned char* wbuf = smem + wave * WAVESTG;
  // per-block column-phase rotation (channel decorrelation)
  const int off1 = (blockIdx.x * 7) & 31;
  const int off2 = (blockIdx.x * 5) & 15;

  // ---------------- Phase 1: r = (src-base) @ W over this wave's K half ---
  f32x4v acc[4];
  #pragma unroll
  for (int t = 0; t < 4; ++t) acc[t] = (f32x4v){0.f, 0.f, 0.f, 0.f};

  // stage one 64-float K-chunk of base+src for 16 rows into buffer p (8KB)
  auto stage = [&](int p, int c) {
    const int chc = (c + off1) & 31;                   // rotated chunk id
    const int kb = kh * 2048 + chc * 64;               // floats
    unsigned char* buf = wbuf + p * 8192;
    #pragma unroll
    for (int i = 0; i < 4; ++i) {
      const int  r  = i * 4 + g;                       // row_local 0..15
      const unsigned cb = ((unsigned)(l4 * 16)) ^ ((unsigned)(r & 7) << 4);
      const long goff = (rowg + r) * (long)D_DIM + kb + (cb >> 2);
      async_ld16(base + goff, buf + i * 1024);         // dest: uniform + lane*16
      async_ld16(srcp + goff, buf + 4096 + i * 1024);
    }
  };

  auto compute = [&](int p, int c) {
    const int chc = (c + off1) & 31;                   // rotated chunk id
    const int kb = kh * 2048 + chc * 64;
    const unsigned char* buf = wbuf + p * 8192;
    uint4 af[2];
    #pragma unroll
    for (int s = 0; s < 2; ++s) {
      const unsigned x = (unsigned)(l4 & 7) << 4;
      const unsigned cb0 = ((unsigned)(s * 128 + g * 32 +  0)) ^ x;
      const unsigned cb1 = ((unsigned)(s * 128 + g * 32 + 16)) ^ x;
      float4 fb0 = *(const float4*)(buf + l4 * 256 + cb0);
      float4 fb1 = *(const float4*)(buf + l4 * 256 + cb1);
      float4 fs0 = *(const float4*)(buf + 4096 + l4 * 256 + cb0);
      float4 fs1 = *(const float4*)(buf + 4096 + l4 * 256 + cb1);
      af[s].x = pack2bf(fs0.x - fb0.x, fs0.y - fb0.y);
      af[s].y = pack2bf(fs0.z - fb0.z, fs0.w - fb0.w);
      af[s].z = pack2bf(fs1.x - fb1.x, fs1.y - fb1.y);
      af[s].w = pack2bf(fs1.z - fb1.z, fs1.w - fb1.w);
    }
    #pragma unroll
    for (int t = 0; t < 4; ++t) {
      #pragma unroll
      for (int s = 0; s < 2; ++s) {
        uint4 bfrag;
        if (USE_WS) {
          bfrag = *(const uint4*)(Wt_bf + (size_t)(t * 16 + l4) * D_DIM +
                                  kb + s * 32 + g * 8);
        } else {
          unsigned int pq[4];
          #pragma unroll
          for (int e2 = 0; e2 < 4; ++e2) {
            float wa = W[(size_t)(kb + s * 32 + g * 8 + e2 * 2    ) * R_DIM + t * 16 + l4];
            float wb = W[(size_t)(kb + s * 32 + g * 8 + e2 * 2 + 1) * R_DIM + t * 16 + l4];
            pq[e2] = pack2bf(wa, wb);
          }
          bfrag.x = pq[0]; bfrag.y = pq[1]; bfrag.z = pq[2]; bfrag.w = pq[3];
        }
        acc[t] = __builtin_amdgcn_mfma_f32_16x16x32_bf16(
            __builtin_bit_cast(bf16vec8, af[s]),
            __builtin_bit_cast(bf16vec8, bfrag), acc[t], 0, 0, 0);
      }
    }
  };

  stage(0, 0);
  #pragma unroll 1
  for (int c = 0; c < 31; ++c) {
    stage((c + 1) & 1, c + 1);     // prefetch next chunk (async, no VGPRs)
    compute(c & 1, c);
  }
  compute(1, 31);

  // per-wave partials -> own staging buf0 (dead now): [16][72] f32
  {
    float* part = (float*)wbuf;
    #pragma unroll
    for (int t = 0; t < 4; ++t)
      #pragma unroll
      for (int i = 0; i < 4; ++i)
        part[(g * 4 + i) * 72 + t * 16 + l4] = acc[t][i];
  }
  __syncthreads();

  // ---------------- Reduce K-halves + per-row partition mask --------------
  {
    const int row = tid >> 3, jg = tid & 7;     // 32 rows x 8 j-groups
    const int lr  = row & 15;
    const float* pa = (const float*)(smem + ((row >> 4) * 2 + 0) * WAVESTG);
    const float* pb = (const float*)(smem + ((row >> 4) * 2 + 1) * WAVESTG);
    int4 sb = *(const int4*)(subs + (rowbase + row) * 4);
    unsigned mbits = (1u << sb.x) | (1u << sb.y) | (1u << sb.z) | (1u << sb.w);
    unsigned short v[8];
    #pragma unroll
    for (int jj = 0; jj < 8; ++jj) {
      const int j = jg * 8 + jj;
      float sum = pa[lr * 72 + j] + pb[lr * 72 + j];
      v[jj] = ((mbits >> (j >> 3)) & 1u) ? (unsigned short)f2bf_u(sum)
                                         : (unsigned short)0;
    }
    uint4 pk;
    pk.x = (unsigned)v[0] | ((unsigned)v[1] << 16);
    pk.y = (unsigned)v[2] | ((unsigned)v[3] << 16);
    pk.z = (unsigned)v[4] | ((unsigned)v[5] << 16);
    pk.w = (unsigned)v[6] | ((unsigned)v[7] << 16);
    *(uint4*)(smem + OFF_RM + row * 144 + jg * 16) = pk;   // stride 72 shorts
  }
  __syncthreads();

  // ---------------- Phase 2: out = base(global) + rm @ W^T ----------------
  uint4 a2[2][2];     // [row-tile m][k-split s], loaded once (rm is 32x64)
  #pragma unroll
  for (int m = 0; m < 2; ++m)
    #pragma unroll
    for (int s = 0; s < 2; ++s)
      a2[m][s] = *(const uint4*)(smem + OFF_RM + (m * 16 + l4) * 144 +
                                 s * 64 + g * 16);
  float* cbuf = (float*)wbuf;     // [32][72] f32 = 9216 B, wave-private
  #pragma unroll 1
  for (int grp = 0; grp < 16; ++grp) {
    const int ga = (grp + off2) & 15;           // rotated column group
    const int cbase = wave * 1024 + ga * 64;
    // base re-read (L2/L3-hot), issued early, independent of MFMAs
    float4 bb[8];
    #pragma unroll
    for (int v2 = 0; v2 < 8; ++v2) {
      const int r = g + v2 * 4;
      bb[v2] = *(const float4*)(base + (rowbase + r) * D_DIM + cbase + l4 * 4);
    }
    f32x4v a[2][4];
    #pragma unroll
    for (int m = 0; m < 2; ++m)
      #pragma unroll
      for (int t = 0; t < 4; ++t) a[m][t] = (f32x4v){0.f, 0.f, 0.f, 0.f};
    #pragma unroll
    for (int t = 0; t < 4; ++t) {
      #pragma unroll
      for (int s = 0; s < 2; ++s) {
        uint4 bfrag;  // B[kk=j][n=col] = W[col][j]; per-lane 8 consecutive j
        if (USE_WS) {
          bfrag = *(const uint4*)(Wb_bf + (size_t)(cbase + t * 16 + l4) * R_DIM +
                                  s * 32 + g * 8);
        } else {
          const float* wp = W + (size_t)(cbase + t * 16 + l4) * R_DIM + s * 32 + g * 8;
          float4 wa = *(const float4*)(wp);
          float4 wb2 = *(const float4*)(wp + 4);
          bfrag.x = pack2bf(wa.x, wa.y); bfrag.y = pack2bf(wa.z, wa.w);
          bfrag.z = pack2bf(wb2.x, wb2.y); bfrag.w = pack2bf(wb2.z, wb2.w);
        }
        #pragma unroll
        for (int m = 0; m < 2; ++m)
          a[m][t] = __builtin_amdgcn_mfma_f32_16x16x32_bf16(
              __builtin_bit_cast(bf16vec8, a2[m][s]),
              __builtin_bit_cast(bf16vec8, bfrag), a[m][t], 0, 0, 0);
      }
    }
    #pragma unroll
    for (int m = 0; m < 2; ++m)
      #pragma unroll
      for (int t = 0; t < 4; ++t)
        #pragma unroll
        for (int i = 0; i < 4; ++i)
          cbuf[(m * 16 + g * 4 + i) * 72 + t * 16 + l4] = a[m][t][i];
    // transpose via wave-local LDS -> coalesced float4 stores
    #pragma unroll
    for (int v2 = 0; v2 < 8; ++v2) {
      const int r = g + v2 * 4;
      f32x4v cv = *(const f32x4v*)(cbuf + r * 72 + l4 * 4);
      float4 o;
      o.x = cv[0] + bb[v2].x;
      o.y = cv[1] + bb[v2].y;
      o.z = cv[2] + bb[v2].z;
      o.w = cv[3] + bb[v2].w;
      *(float4*)(out + (rowbase + r) * D_DIM + cbase + l4 * 4) = o;
    }
  }
}

extern "C" void kernel_launch(void* const* d_in, const int* in_sizes, int n_in,
                              void* d_out, int out_size, void* d_ws, size_t ws_size,
                              hipStream_t stream) {
  const float* base = (const float*)d_in[0];
  const float* srcp = (const float*)d_in[1];
  const float* W    = (const float*)d_in[2];
  const int*   subs = (const int*)d_in[3];
  float* out = (float*)d_out;

  const int nblocks = 16384 / BM;   // 512
  const size_t wbytes = (size_t)2 * R_DIM * D_DIM * sizeof(unsigned short); // 1 MB
  if (d_ws && ws_size >= wbytes) {
    unsigned short* Wt = (unsigned short*)d_ws;          // [64][4096] bf16
    unsigned short* Wb = Wt + (size_t)R_DIM * D_DIM;     // [4096][64] bf16
    lrri_prep<<<256, 256, 0, stream>>>(W, Wt, Wb);
    lrri_fused<true><<<nblocks, 256, 0, stream>>>(base, srcp, W, subs, Wt, Wb, out);
  } else {
    lrri_fused<false><<<nblocks, 256, 0, stream>>>(base, srcp, W, subs, nullptr, nullptr, out);
  }
}